// Round 1
// baseline (10035.096 us; speedup 1.0000x reference)
//
#include <hip/hip_runtime.h>

#define BATCH 8
#define N 32768
#define NPOINT 2048
#define NT 512              // threads per block (8 waves)
#define PPT (N / NT)        // 64 points per thread
#define NW (NT / 64)        // 8 waves

// One block per batch. Coordinates in registers, running-min temp[] in LDS
// (point-major p = k*NT + t -> bank = t%32, conflict-free). Exact f32
// semantics of the numpy reference: separate mul/add (contract off),
// argmax ties -> lowest index.
__global__ __launch_bounds__(NT, 2)
void fps_kernel(const float* __restrict__ pts_t,  // (B,3,N)
                float* __restrict__ out)          // (B,3,NPOINT)
{
#pragma clang fp contract(off)
    __shared__ float s_temp[N];       // 128 KiB of the 160 KiB/CU
    __shared__ float s_wmax[NW];
    __shared__ int   s_besti[2];      // double-buffered: reset w/o extra barrier

    const int b = blockIdx.x;
    const int t = threadIdx.x;
    const int wv = t >> 6;

    const float* __restrict__ px = pts_t + (size_t)b * 3 * N;
    const float* __restrict__ py = px + N;
    const float* __restrict__ pz = py + N;
    float* outx = out + (size_t)b * 3 * NPOINT;
    float* outy = outx + NPOINT;
    float* outz = outy + NPOINT;

    // Load this thread's 64 points into registers (coalesced: p = k*NT + t).
    float x[PPT], y[PPT], z[PPT];
#pragma unroll
    for (int k = 0; k < PPT; ++k) {
        const int p = k * NT + t;
        x[k] = px[p];
        y[k] = py[p];
        z[k] = pz[p];
        s_temp[p] = 1e10f;
    }

    // First selected index is 0 (reference: idx[0] = 0).
    float lx = px[0], ly = py[0], lz = pz[0];
    if (t == 0) {
        outx[0] = lx; outy[0] = ly; outz[0] = lz;
        s_besti[0] = N;
        s_besti[1] = N;
    }
    __syncthreads();

    for (int j = 1; j < NPOINT; ++j) {
        // --- update temps vs last point; track local max ---
        float vmax = 0.0f;
#pragma unroll
        for (int k = 0; k < PPT; ++k) {
            const int p = k * NT + t;
            float dx = x[k] - lx;
            float dy = y[k] - ly;
            float dz = z[k] - lz;
            float d2 = (dx * dx + dy * dy) + dz * dz;   // numpy order, no fma
            float tm = fminf(s_temp[p], d2);
            s_temp[p] = tm;
            vmax = fmaxf(vmax, tm);
        }

        // --- wave max (all lanes end with wave max) ---
#pragma unroll
        for (int off = 32; off >= 1; off >>= 1)
            vmax = fmaxf(vmax, __shfl_xor(vmax, off));
        if ((t & 63) == 0) s_wmax[wv] = vmax;
        __syncthreads();                       // barrier 1

        if (t == 0) s_besti[(j + 1) & 1] = N;  // prep other slot for next iter

        // every thread redundantly reduces the 8 wave maxima (LDS broadcast)
        float M = s_wmax[0];
#pragma unroll
        for (int w = 1; w < NW; ++w) M = fmaxf(M, s_wmax[w]);

        // --- lazy argmax: only the wave(s) holding M rescan for the index ---
        if (vmax == M) {
            int cand = N;
#pragma unroll
            for (int k = PPT - 1; k >= 0; --k) {   // descending -> keep lowest p
                const int p = k * NT + t;
                cand = (s_temp[p] == M) ? p : cand;
            }
            if (cand < N) atomicMin(&s_besti[j & 1], cand);
        }
        __syncthreads();                       // barrier 2

        const int sel = __builtin_amdgcn_readfirstlane(s_besti[j & 1]);
        lx = px[sel];
        ly = py[sel];
        lz = pz[sel];
        if (t == 0) { outx[j] = lx; outy[j] = ly; outz[j] = lz; }
    }
}

extern "C" void kernel_launch(void* const* d_in, const int* in_sizes, int n_in,
                              void* d_out, int out_size, void* d_ws, size_t ws_size,
                              hipStream_t stream) {
    // d_in[0]: points_xyz (B,N,3) — unused (same values as transposed copy)
    // d_in[1]: points_xyz_t (B,3,N)
    // d_in[2]: features_with_xyz (B,67,N) — unused
    const float* pts_t = (const float*)d_in[1];
    float* out = (float*)d_out;
    fps_kernel<<<BATCH, NT, 0, stream>>>(pts_t, out);
}

// Round 2
// 6704.250 us; speedup vs baseline: 1.4968x; 1.4968x over previous
//
#include <hip/hip_runtime.h>

#define BATCH 8
#define N 32768
#define NPOINT 2048
#define NT 512               // threads per block (8 waves)
#define NPAIR (N / 2 / NT)   // 32 float2 point-pairs per thread
#define NW (NT / 64)

typedef __attribute__((ext_vector_type(2))) float f2;

// One block per batch. Coordinates live in VGPRs as float2 (192 regs, pinned
// by waves_per_eu(2,2) budget=256 + a compiler memory barrier that makes
// reload-from-global illegal). Running-min temp[] in LDS as float2,
// q = k*NT + t (thread-private slots, conflict-free ds_*_b64).
// Bit-exact numpy semantics: contract off, (xx+yy)+zz order, min-index ties.
__global__ __attribute__((amdgpu_flat_work_group_size(NT, NT),
                          amdgpu_waves_per_eu(2, 2)))
void fps_kernel(const float* __restrict__ pts_t,  // (B,3,N)
                float* __restrict__ out)          // (B,3,NPOINT)
{
#pragma clang fp contract(off)
    __shared__ f2    s_temp[N / 2];   // 128 KiB
    __shared__ float s_wmax[NW];
    __shared__ int   s_besti[2];      // double-buffered

    const int b = blockIdx.x;
    const int t = threadIdx.x;
    const int wv = t >> 6;

    const float* __restrict__ px = pts_t + (size_t)b * 3 * N;
    const float* __restrict__ py = px + N;
    const float* __restrict__ pz = py + N;
    const f2* __restrict__ px2 = (const f2*)px;
    const f2* __restrict__ py2 = (const f2*)py;
    const f2* __restrict__ pz2 = (const f2*)pz;
    float* outx = out + (size_t)b * 3 * NPOINT;
    float* outy = outx + NPOINT;
    float* outz = outy + NPOINT;

    // Load this thread's 32 coordinate pairs into registers (coalesced 8B).
    f2 x2[NPAIR], y2[NPAIR], z2[NPAIR];
#pragma unroll
    for (int k = 0; k < NPAIR; ++k) {
        const int q = k * NT + t;
        x2[k] = px2[q];
        y2[k] = py2[q];
        z2[k] = pz2[q];
        s_temp[q] = (f2){1e10f, 1e10f};
    }
    // Compiler barrier: memory may have "changed", so the loaded coord values
    // can no longer be rematerialized from global — they must stay in VGPRs.
    asm volatile("" ::: "memory");

    // First selected index is 0 (reference: idx[0] = 0).
    float lx = px[0], ly = py[0], lz = pz[0];
    if (t == 0) {
        outx[0] = lx; outy[0] = ly; outz[0] = lz;
        s_besti[0] = N;
        s_besti[1] = N;
    }
    __syncthreads();

    for (int j = 1; j < NPOINT; ++j) {
        const f2 lx2 = (f2){lx, lx};
        const f2 ly2 = (f2){ly, ly};
        const f2 lz2 = (f2){lz, lz};

        // --- update temps vs last pivot; track per-component running max ---
        f2 mx = (f2){0.0f, 0.0f};
#pragma unroll
        for (int k = 0; k < NPAIR; ++k) {
            const int q = k * NT + t;
            f2 dx = x2[k] - lx2;             // v_pk_add_f32 (neg)
            f2 dy = y2[k] - ly2;
            f2 dz = z2[k] - lz2;
            f2 sx = dx * dx;                 // v_pk_mul_f32
            f2 sy = dy * dy;
            f2 sz = dz * dz;
            f2 s = (sx + sy) + sz;           // numpy order, no fma
            f2 tm = s_temp[q];               // ds_read_b64
            tm.x = fminf(tm.x, s.x);
            tm.y = fminf(tm.y, s.y);
            s_temp[q] = tm;                  // ds_write_b64
            mx.x = fmaxf(mx.x, tm.x);
            mx.y = fmaxf(mx.y, tm.y);
        }
        float vmax = fmaxf(mx.x, mx.y);

        // --- wave max (all lanes end with wave max) ---
#pragma unroll
        for (int off = 32; off >= 1; off >>= 1)
            vmax = fmaxf(vmax, __shfl_xor(vmax, off));
        if ((t & 63) == 0) s_wmax[wv] = vmax;
        __syncthreads();                       // barrier 1

        if (t == 0) s_besti[(j + 1) & 1] = N;  // prep other slot for next iter

        // every thread redundantly reduces the 8 wave maxima (LDS broadcast)
        float M = s_wmax[0];
#pragma unroll
        for (int w = 1; w < NW; ++w) M = fmaxf(M, s_wmax[w]);

        // --- lazy argmax: only the wave(s) holding M rescan for the index ---
        if (vmax == M) {                       // wave-uniform branch
            int cand = N;
#pragma unroll
            for (int k = NPAIR - 1; k >= 0; --k) {  // descending -> lowest idx wins
                const int q = k * NT + t;
                f2 tm = s_temp[q];
                cand = (tm.y == M) ? 2 * q + 1 : cand;
                cand = (tm.x == M) ? 2 * q : cand;
            }
            if (cand < N) atomicMin(&s_besti[j & 1], cand);
        }
        __syncthreads();                       // barrier 2

        const int sel = __builtin_amdgcn_readfirstlane(s_besti[j & 1]);
        lx = px[sel];                          // uniform -> s_load, L2-warm
        ly = py[sel];
        lz = pz[sel];
        if (t == 0) { outx[j] = lx; outy[j] = ly; outz[j] = lz; }
    }
}

extern "C" void kernel_launch(void* const* d_in, const int* in_sizes, int n_in,
                              void* d_out, int out_size, void* d_ws, size_t ws_size,
                              hipStream_t stream) {
    // d_in[0]: points_xyz (B,N,3) — unused
    // d_in[1]: points_xyz_t (B,3,N)
    // d_in[2]: features_with_xyz (B,67,N) — unused
    const float* pts_t = (const float*)d_in[1];
    float* out = (float*)d_out;
    fps_kernel<<<BATCH, NT, 0, stream>>>(pts_t, out);
}

// Round 3
// 5813.902 us; speedup vs baseline: 1.7261x; 1.1531x over previous
//
#include <hip/hip_runtime.h>

#define BATCH 8
#define N 32768
#define NPOINT 2048
#define NT 512               // threads per block (8 waves)
#define NW (NT / 64)

typedef __attribute__((ext_vector_type(2))) float f2;

// One block per batch.
//   x,y,temp : 96 individually-named f2 register variables (192 VGPRs)
//   z        : LDS (128 KiB, q = k*NT + t, conflict-free ds_read_b64)
// Per iteration: 32 ds_read_b64 (z) + ~384 VALU, zero LDS writes.
// Bit-exact numpy semantics: contract off, (xx+yy)+zz order, lowest-index ties.

#define REP32(M)  M(0)  M(1)  M(2)  M(3)  M(4)  M(5)  M(6)  M(7)  \
                  M(8)  M(9)  M(10) M(11) M(12) M(13) M(14) M(15) \
                  M(16) M(17) M(18) M(19) M(20) M(21) M(22) M(23) \
                  M(24) M(25) M(26) M(27) M(28) M(29) M(30) M(31)

#define REP32R(M) M(31) M(30) M(29) M(28) M(27) M(26) M(25) M(24) \
                  M(23) M(22) M(21) M(20) M(19) M(18) M(17) M(16) \
                  M(15) M(14) M(13) M(12) M(11) M(10) M(9)  M(8)  \
                  M(7)  M(6)  M(5)  M(4)  M(3)  M(2)  M(1)  M(0)

__global__ __attribute__((amdgpu_flat_work_group_size(NT, NT),
                          amdgpu_waves_per_eu(2, 2)))
void fps_kernel(const float* __restrict__ pts_t,  // (B,3,N)
                float* __restrict__ out)          // (B,3,NPOINT)
{
#pragma clang fp contract(off)
    __shared__ f2    s_z[N / 2];      // 128 KiB
    __shared__ float s_wmax[NW];
    __shared__ int   s_besti[2];      // double-buffered

    const int b = blockIdx.x;
    const int t = threadIdx.x;
    const int wv = t >> 6;

    const float* __restrict__ px = pts_t + (size_t)b * 3 * N;
    const float* __restrict__ py = px + N;
    const float* __restrict__ pz = py + N;
    const f2* __restrict__ px2 = (const f2*)px;
    const f2* __restrict__ py2 = (const f2*)py;
    const f2* __restrict__ pz2 = (const f2*)pz;
    float* outx = out + (size_t)b * 3 * NPOINT;
    float* outy = outx + NPOINT;
    float* outz = outy + NPOINT;

    // ---- declare 96 named f2 registers ----
#define DECL(k) f2 x##k, y##k, T##k;
    REP32(DECL)
#undef DECL

    // ---- load x,y into registers; z into LDS; init temps ----
#define LOADK(k) { const int q = (k) * NT + t;               \
                   x##k = px2[q];  y##k = py2[q];            \
                   s_z[q] = pz2[q];                          \
                   T##k = (f2){1e10f, 1e10f}; }
    REP32(LOADK)
#undef LOADK

    // First selected index is 0 (reference: idx[0] = 0).
    float lx = px[0], ly = py[0], lz = pz[0];
    if (t == 0) {
        outx[0] = lx; outy[0] = ly; outz[0] = lz;
        s_besti[0] = N;
        s_besti[1] = N;
    }
    __syncthreads();

    for (int j = 1; j < NPOINT; ++j) {
        const f2 lx2 = (f2){lx, lx};
        const f2 ly2 = (f2){ly, ly};
        const f2 lz2 = (f2){lz, lz};

        // --- update register temps vs pivot; track running max ---
        f2 mx = (f2){0.0f, 0.0f};
#define UPD(k) { const int q = (k) * NT + t;                         \
                 f2 dz = s_z[q] - lz2;                               \
                 f2 dx = x##k - lx2;                                 \
                 f2 dy = y##k - ly2;                                 \
                 f2 s  = (dx * dx + dy * dy) + dz * dz;  /* numpy order */ \
                 T##k.x = fminf(T##k.x, s.x);                        \
                 T##k.y = fminf(T##k.y, s.y);                        \
                 mx.x = fmaxf(mx.x, T##k.x);                         \
                 mx.y = fmaxf(mx.y, T##k.y); }
        REP32(UPD)
#undef UPD
        float vmax = fmaxf(mx.x, mx.y);

        // --- wave max (all lanes end with wave max) ---
#pragma unroll
        for (int off = 32; off >= 1; off >>= 1)
            vmax = fmaxf(vmax, __shfl_xor(vmax, off));
        if ((t & 63) == 0) s_wmax[wv] = vmax;
        __syncthreads();                       // barrier 1

        if (t == 0) s_besti[(j + 1) & 1] = N;  // prep other slot for next iter

        // every thread redundantly reduces the 8 wave maxima (LDS broadcast)
        float M = s_wmax[0];
#pragma unroll
        for (int w = 1; w < NW; ++w) M = fmaxf(M, s_wmax[w]);

        // --- lazy argmax: only the wave(s) holding M rescan (registers) ---
        if (vmax == M) {                       // wave-uniform branch
            int cand = N;
#define SCAN(k) { const int q = (k) * NT + t;                 \
                  cand = (T##k.y == M) ? 2 * q + 1 : cand;    \
                  cand = (T##k.x == M) ? 2 * q     : cand; }
            REP32R(SCAN)                       // descending -> lowest idx wins
#undef SCAN
            if (cand < N) atomicMin(&s_besti[j & 1], cand);
        }
        __syncthreads();                       // barrier 2

        const int sel = __builtin_amdgcn_readfirstlane(s_besti[j & 1]);
        lx = px[sel];                          // uniform -> scalar load
        ly = py[sel];
        lz = pz[sel];
        if (t == 0) { outx[j] = lx; outy[j] = ly; outz[j] = lz; }
    }
}

extern "C" void kernel_launch(void* const* d_in, const int* in_sizes, int n_in,
                              void* d_out, int out_size, void* d_ws, size_t ws_size,
                              hipStream_t stream) {
    // d_in[0]: points_xyz (B,N,3) — unused
    // d_in[1]: points_xyz_t (B,3,N)
    // d_in[2]: features_with_xyz (B,67,N) — unused
    const float* pts_t = (const float*)d_in[1];
    float* out = (float*)d_out;
    fps_kernel<<<BATCH, NT, 0, stream>>>(pts_t, out);
}